// Round 1
// baseline (1856.719 us; speedup 1.0000x reference)
//
#include <hip/hip_runtime.h>
#include <math.h>

#define BB   64
#define SS   1024
#define DD   256
#define H2   512
#define FF   128
#define TT   64
#define NSEG 128
#define DIN  1152
#define G4   2048
#define MROWS 8192   /* B*NSEG */
#define MX   65536   /* B*S   */

typedef __attribute__((ext_vector_type(8))) short bf16x8;
typedef __attribute__((ext_vector_type(4))) float f32x4;

__device__ __forceinline__ unsigned short f2b(float f){
    union { float f; unsigned u; } v; v.f = f;
    unsigned r = v.u + 0x7fffu + ((v.u >> 16) & 1u);
    return (unsigned short)(r >> 16);
}
__device__ __forceinline__ float b2f(unsigned short h){
    union { unsigned u; float f; } v; v.u = ((unsigned)h) << 16;
    return v.f;
}

// ---------------- prep kernels ----------------

__global__ void k_cvt(const float* __restrict__ src, unsigned short* __restrict__ dst, int n){
    int i = blockIdx.x * 256 + threadIdx.x;
    if (i < n) dst[i] = f2b(src[i]);
}

// Wf [768][256] rows: 0..127 c1t0 | 128..255 c2t0 | 256..383 c2t1 | 384..511 c3t0 | 512..639 c3t1 | 640..767 c3t2
__global__ void k_wf(const float* __restrict__ w1, const float* __restrict__ w2,
                     const float* __restrict__ w3, unsigned short* __restrict__ Wf){
    int i = blockIdx.x * 256 + threadIdx.x;       // 768*256
    int col = i >> 8, d = i & 255;
    float v;
    if (col < 128)      v = w1[col * 256 + d];
    else if (col < 384) { int f = (col - 128) & 127; int tap = (col - 128) >> 7; v = w2[f * 512 + tap * 256 + d]; }
    else                { int c = col - 384; int f = c & 127; int tap = c >> 7;  v = w3[f * 768 + tap * 256 + d]; }
    Wf[i] = f2b(v);
}

// W_fc [64][512] -> W_fc_t [512][64] fp32
__global__ void k_tr_wfc(const float* __restrict__ src, float* __restrict__ dst){
    int i = blockIdx.x * 256 + threadIdx.x;       // 32768
    int v = i >> 9, k = i & 511;
    dst[k * 64 + v] = src[i];
}

// X[row][d] = bf16(embed[word_ids[row]][d]), row in [0, MX)
__global__ void k_gather(const int* __restrict__ wid, const float* __restrict__ embed,
                         unsigned short* __restrict__ X){
    int i = blockIdx.x * 256 + threadIdx.x;       // MX*64
    int row = i >> 6, d4 = i & 63;
    int w = wid[row];
    float4 v = *(const float4*)(embed + (size_t)w * DD + d4 * 4);
    ushort4 o; o.x = f2b(v.x); o.y = f2b(v.y); o.z = f2b(v.z); o.w = f2b(v.w);
    *(ushort4*)(X + (size_t)row * DD + d4 * 4) = o;
}

// c_w: dec[row][0..256) = mean of 8 X rows
__global__ void k_cw(const unsigned short* __restrict__ X, unsigned short* __restrict__ dec){
    int i = blockIdx.x * 256 + threadIdx.x;       // MROWS*256
    int row = i >> 8, d = i & 255;
    const unsigned short* p = X + (size_t)row * 8 * DD + d;
    float s = 0.f;
#pragma unroll
    for (int t = 0; t < 8; t++) s += b2f(p[t * DD]);
    dec[(size_t)row * DIN + d] = f2b(s * 0.125f);
}

// c_h: dec[row][256..768) = mean of 8 encoder rows
__global__ void k_ch(const float* __restrict__ enc, unsigned short* __restrict__ dec){
    int i = blockIdx.x * 256 + threadIdx.x;       // MROWS*512
    int row = i >> 9, c = i & 511;
    const float* p = enc + (size_t)row * 8 * H2 + c;
    float s = 0.f;
#pragma unroll
    for (int t = 0; t < 8; t++) s += p[t * H2];
    dec[(size_t)row * DIN + 256 + c] = f2b(s * 0.125f);
}

// h0 into Hbuf[0], column-blocked layout: elem (b,c) at (c>>3)*512 + b*8 + (c&7)
__global__ void k_h0(const float* __restrict__ enc, unsigned short* __restrict__ Hbuf){
    int i = blockIdx.x * 256 + threadIdx.x;       // 64*512
    int b = i >> 9, c = i & 511;
    float v = (c < 256) ? enc[(size_t)b * SS * H2 + (size_t)(SS - 1) * H2 + c]
                        : enc[(size_t)b * SS * H2 + c];
    Hbuf[(size_t)(c >> 3) * 512 + b * 8 + (c & 7)] = f2b(v);
}

// ---------------- generic BT GEMM: C[M][N] = A[M][K] * Bm[N][K]^T, bf16 in/out ----------------
__global__ __launch_bounds__(256) void gemm_bt(
    const unsigned short* __restrict__ A, const unsigned short* __restrict__ Bm,
    unsigned short* __restrict__ C, int M, int N, int K)
{
    __shared__ unsigned short As[128][40];   // +8 pad: 2-way-max banks, 16B-aligned rows
    __shared__ unsigned short Bs[128][40];
    const int tid = threadIdx.x;
    const int m0 = blockIdx.y * 128, n0 = blockIdx.x * 128;
    const int w = tid >> 6, lane = tid & 63;
    const int lm = lane & 15, quad = lane >> 4;
    const int wm = (w >> 1) * 64, wn = (w & 1) * 64;

    const f32x4 z = {0.f, 0.f, 0.f, 0.f};
    f32x4 acc[4][4];
#pragma unroll
    for (int i = 0; i < 4; i++)
#pragma unroll
        for (int j = 0; j < 4; j++) acc[i][j] = z;

    const int r0 = tid >> 2;            // 0..63
    const int kp = (tid & 3) * 8;       // 0,8,16,24 (bf16 units)

    for (int kc = 0; kc < K; kc += 32){
        uint4 a0 = *(const uint4*)(A + (size_t)(m0 + r0) * K + kc + kp);
        uint4 a1 = *(const uint4*)(A + (size_t)(m0 + 64 + r0) * K + kc + kp);
        uint4 b0 = *(const uint4*)(Bm + (size_t)(n0 + r0) * K + kc + kp);
        uint4 b1 = *(const uint4*)(Bm + (size_t)(n0 + 64 + r0) * K + kc + kp);
        __syncthreads();
        *(uint4*)&As[r0][kp] = a0;
        *(uint4*)&As[64 + r0][kp] = a1;
        *(uint4*)&Bs[r0][kp] = b0;
        *(uint4*)&Bs[64 + r0][kp] = b1;
        __syncthreads();
        bf16x8 af[4], bf[4];
#pragma unroll
        for (int mt = 0; mt < 4; mt++) af[mt] = *(const bf16x8*)&As[wm + mt * 16 + lm][quad * 8];
#pragma unroll
        for (int nt = 0; nt < 4; nt++) bf[nt] = *(const bf16x8*)&Bs[wn + nt * 16 + lm][quad * 8];
#pragma unroll
        for (int mt = 0; mt < 4; mt++)
#pragma unroll
            for (int nt = 0; nt < 4; nt++)
                acc[mt][nt] = __builtin_amdgcn_mfma_f32_16x16x32_bf16(af[mt], bf[nt], acc[mt][nt], 0, 0, 0);
    }
#pragma unroll
    for (int mt = 0; mt < 4; mt++){
        int mrow = m0 + wm + mt * 16 + quad * 4;
#pragma unroll
        for (int nt = 0; nt < 4; nt++){
            int ncol = n0 + wn + nt * 16 + lm;
#pragma unroll
            for (int r = 0; r < 4; r++)
                C[(size_t)(mrow + r) * N + ncol] = f2b(acc[mt][nt][r]);
        }
    }
}

// ---------------- conv max-pool: G[MX rows][N] -> dec[:,768+colofs..] ----------------
__global__ void k_pool(const unsigned short* __restrict__ G, const float* __restrict__ bias,
                       unsigned short* __restrict__ dec, int taps, int colofs){
    int i = blockIdx.x * 256 + threadIdx.x;       // MROWS*128
    int row = i >> 7, f = i & 127;
    int N = taps * 128;
    float mx = -1e30f;
    for (int t = 0; t <= 8 - taps; t++){
        float a = 0.f;
        for (int tap = 0; tap < taps; tap++)
            a += b2f(G[(size_t)(row * 8 + t + tap) * N + tap * 128 + f]);
        mx = fmaxf(mx, a);
    }
    mx = fmaxf(mx + bias[f], 0.f);
    dec[(size_t)row * DIN + 768 + colofs + f] = f2b(mx);
}

// ---------------- persistent LSTM recurrence: 64 blocks, flag-synced ----------------
// Hbuf layout per step: [kb:64][b:64][c':8] bf16 (column-blocked; block cb owns kb==cb)
__global__ __launch_bounds__(256, 1) void k_lstm(
    const unsigned short* __restrict__ gx,   // [MROWS][2048] bf16, row = b*128+t
    const unsigned short* __restrict__ Whh,  // [2048][512] bf16
    unsigned short* __restrict__ Hbuf,       // [129][64*512]
    int* cnt)                                // [128]
{
    __shared__ unsigned short Wl[32][520];   // rows: 8 i | 8 f | 8 g | 8 o for cols c0..c0+7
    const int tid = threadIdx.x;
    const int cb = blockIdx.x;
    const int c0 = cb * 8;
    const int w = tid >> 6, lane = tid & 63, lm = lane & 15, quad = lane >> 4;

#pragma unroll
    for (int i = 0; i < 8; i++){
        int u = tid + i * 256;                    // 0..2047
        int r = u >> 6, k8 = (u & 63) * 8;
        int g = r >> 3, c = r & 7;
        *(uint4*)&Wl[r][k8] = *(const uint4*)(Whh + (size_t)(g * H2 + c0 + c) * H2 + k8);
    }
    __syncthreads();

    float cst[4] = {0.f, 0.f, 0.f, 0.f};

    for (int t = 0; t < NSEG; t++){
        if (t > 0){
            if (tid == 0){
                while (__hip_atomic_fetch_add(cnt + (t - 1), 0, __ATOMIC_RELAXED, __HIP_MEMORY_SCOPE_AGENT) < 64){}
            }
            __syncthreads();
            __threadfence();   // acquire: invalidate stale L1/L2 before reading peers' h
        }
        const unsigned short* hp = Hbuf + (size_t)t * (BB * H2);
        f32x4 acc0 = {0.f,0.f,0.f,0.f}, acc1 = {0.f,0.f,0.f,0.f};
#pragma unroll
        for (int ks = 0; ks < 16; ks++){
            bf16x8 av = *(const bf16x8*)(hp + (size_t)(ks * 4 + quad) * 512 + (w * 16 + lm) * 8);
            bf16x8 b0 = *(const bf16x8*)&Wl[lm][ks * 32 + quad * 8];
            bf16x8 b1 = *(const bf16x8*)&Wl[16 + lm][ks * 32 + quad * 8];
            acc0 = __builtin_amdgcn_mfma_f32_16x16x32_bf16(av, b0, acc0, 0, 0, 0);
            acc1 = __builtin_amdgcn_mfma_f32_16x16x32_bf16(av, b1, acc1, 0, 0, 0);
        }
        // cols 0..7=i, 8..15=f (acc0); 16..23=g, 24..31=o (acc1). partner lane lm^8 holds f/o.
        float p0[4], p1[4];
#pragma unroll
        for (int r = 0; r < 4; r++){
            p0[r] = __shfl_xor(acc0[r], 8);
            p1[r] = __shfl_xor(acc1[r], 8);
        }
        if (lm < 8){
            const int cc = c0 + lm;
            unsigned short* hw = Hbuf + (size_t)(t + 1) * (BB * H2) + (size_t)cb * 512 + lm;
#pragma unroll
            for (int r = 0; r < 4; r++){
                int b = w * 16 + quad * 4 + r;
                const unsigned short* g = gx + (size_t)(b * NSEG + t) * G4 + cc;
                float iv = acc0[r] + b2f(g[0]);
                float fv = p0[r]   + b2f(g[512]);
                float gv = acc1[r] + b2f(g[1024]);
                float ov = p1[r]   + b2f(g[1536]);
                float si = 1.f / (1.f + expf(-iv));
                float sf = 1.f / (1.f + expf(-fv));
                float so = 1.f / (1.f + expf(-ov));
                cst[r] = sf * cst[r] + si * tanhf(gv);
                hw[b * 8] = f2b(so * tanhf(cst[r]));
            }
        }
        __syncthreads();
        if (tid == 0){
            __threadfence();   // release: publish this block's h stores
            __hip_atomic_fetch_add(cnt + t, 1, __ATOMIC_RELEASE, __HIP_MEMORY_SCOPE_AGENT);
        }
    }
}

// ---------------- output projection + log_softmax ----------------
__global__ __launch_bounds__(256) void k_out(
    const unsigned short* __restrict__ Hbuf, const float* __restrict__ Wt, float* __restrict__ out)
{
    __shared__ float hsh[4][H2];
    const int w = threadIdx.x >> 6, lane = threadIdx.x & 63;
    const int row = blockIdx.x * 4 + w;          // 0..8191 = b*128 + t
    const int b = row >> 7, t = row & 127;
    const unsigned short* hp = Hbuf + (size_t)(t + 1) * (BB * H2) + b * 8;
    uint4 hv = *(const uint4*)(hp + (size_t)lane * 512);   // kb = lane
    const unsigned short* hs = (const unsigned short*)&hv;
#pragma unroll
    for (int i = 0; i < 8; i++) hsh[w][lane * 8 + i] = b2f(hs[i]);
    __syncthreads();
    float acc = 0.f;
#pragma unroll 8
    for (int k = 0; k < H2; k++)
        acc = fmaf(hsh[w][k], Wt[k * 64 + lane], acc);
    float m = acc;
#pragma unroll
    for (int off = 32; off; off >>= 1) m = fmaxf(m, __shfl_xor(m, off));
    float e = expf(acc - m), s = e;
#pragma unroll
    for (int off = 32; off; off >>= 1) s += __shfl_xor(s, off);
    out[(size_t)row * TT + lane] = acc - m - logf(s);
}

// ---------------- launcher ----------------
extern "C" void kernel_launch(void* const* d_in, const int* in_sizes, int n_in,
                              void* d_out, int out_size, void* d_ws, size_t ws_size,
                              hipStream_t stream)
{
    const int*   wid = (const int*)d_in[0];
    const float* emb = (const float*)d_in[1];
    const float* enc = (const float*)d_in[2];
    const float* wc1 = (const float*)d_in[3];
    const float* bc1 = (const float*)d_in[4];
    const float* wc2 = (const float*)d_in[5];
    const float* bc2 = (const float*)d_in[6];
    const float* wc3 = (const float*)d_in[7];
    const float* bc3 = (const float*)d_in[8];
    const float* wih = (const float*)d_in[9];
    const float* whh = (const float*)d_in[10];
    const float* wfc = (const float*)d_in[11];

    char* ws = (char*)d_ws;
    size_t off = 0;
    auto alloc = [&](size_t bytes) -> void* {
        void* p = ws + off; off += (bytes + 255) & ~(size_t)255; return p;
    };
    unsigned short* X    = (unsigned short*)alloc((size_t)MX * DD * 2);      // 33.5 MB (reused as Hbuf)
    unsigned short* dec  = (unsigned short*)alloc((size_t)MROWS * DIN * 2);  // 18.9 MB
    unsigned short* Gb   = (unsigned short*)alloc((size_t)MX * 384 * 2);     // 50.3 MB (reused as gates)
    unsigned short* Wfb  = (unsigned short*)alloc((size_t)768 * 256 * 2);
    unsigned short* Wihb = (unsigned short*)alloc((size_t)G4 * DIN * 2);
    unsigned short* Whhb = (unsigned short*)alloc((size_t)G4 * H2 * 2);
    float*          Wfct = (float*)alloc((size_t)H2 * TT * 4);
    int*            cnt  = (int*)alloc(NSEG * 4);
    unsigned short* Hbuf  = X;    // X dead after conv GEMM pass 3
    unsigned short* gates = Gb;   // G dead after pool3

    hipMemsetAsync(cnt, 0, NSEG * 4, stream);
    k_cvt<<<(G4 * DIN + 255) / 256, 256, 0, stream>>>(wih, Wihb, G4 * DIN);
    k_cvt<<<(G4 * H2 + 255) / 256, 256, 0, stream>>>(whh, Whhb, G4 * H2);
    k_wf<<<768, 256, 0, stream>>>(wc1, wc2, wc3, Wfb);
    k_tr_wfc<<<128, 256, 0, stream>>>(wfc, Wfct);
    k_gather<<<MX / 4, 256, 0, stream>>>(wid, emb, X);
    k_cw<<<MROWS, 256, 0, stream>>>(X, dec);
    k_ch<<<MROWS * 2, 256, 0, stream>>>(enc, dec);

    gemm_bt<<<dim3(1, 512), 256, 0, stream>>>(X, Wfb,                         Gb, MX, 128, 256);
    k_pool<<<4096, 256, 0, stream>>>(Gb, bc1, dec, 1, 0);
    gemm_bt<<<dim3(2, 512), 256, 0, stream>>>(X, Wfb + (size_t)128 * 256,     Gb, MX, 256, 256);
    k_pool<<<4096, 256, 0, stream>>>(Gb, bc2, dec, 2, 128);
    gemm_bt<<<dim3(3, 512), 256, 0, stream>>>(X, Wfb + (size_t)384 * 256,     Gb, MX, 384, 256);
    k_pool<<<4096, 256, 0, stream>>>(Gb, bc3, dec, 3, 256);

    k_h0<<<BB * H2 / 256, 256, 0, stream>>>(enc, Hbuf);   // after last X reader
    gemm_bt<<<dim3(16, 64), 256, 0, stream>>>(dec, Wihb, gates, MROWS, G4, DIN);
    k_lstm<<<64, 256, 0, stream>>>(gates, Whhb, Hbuf, cnt);
    k_out<<<2048, 256, 0, stream>>>(Hbuf, Wfct, (float*)d_out);
}

// Round 2
// 1629.604 us; speedup vs baseline: 1.1394x; 1.1394x over previous
//
#include <hip/hip_runtime.h>
#include <math.h>

#define BB   64
#define SS   1024
#define DD   256
#define H2   512
#define FF   128
#define TT   64
#define NSEG 128
#define DIN  1152
#define G4   2048
#define MROWS 8192   /* B*NSEG */
#define MX   65536   /* B*S   */

typedef __attribute__((ext_vector_type(8))) short bf16x8;
typedef __attribute__((ext_vector_type(4))) float f32x4;

__device__ __forceinline__ unsigned short f2b(float f){
    union { float f; unsigned u; } v; v.f = f;
    unsigned r = v.u + 0x7fffu + ((v.u >> 16) & 1u);
    return (unsigned short)(r >> 16);
}
__device__ __forceinline__ float b2f(unsigned short h){
    union { unsigned u; float f; } v; v.u = ((unsigned)h) << 16;
    return v.f;
}

// ---------------- prep kernels ----------------

__global__ void k_cvt(const float* __restrict__ src, unsigned short* __restrict__ dst, int n){
    int i = blockIdx.x * 256 + threadIdx.x;
    if (i < n) dst[i] = f2b(src[i]);
}

// Wf [768][256] rows: 0..127 c1t0 | 128..255 c2t0 | 256..383 c2t1 | 384..511 c3t0 | 512..639 c3t1 | 640..767 c3t2
__global__ void k_wf(const float* __restrict__ w1, const float* __restrict__ w2,
                     const float* __restrict__ w3, unsigned short* __restrict__ Wf){
    int i = blockIdx.x * 256 + threadIdx.x;       // 768*256
    int col = i >> 8, d = i & 255;
    float v;
    if (col < 128)      v = w1[col * 256 + d];
    else if (col < 384) { int f = (col - 128) & 127; int tap = (col - 128) >> 7; v = w2[f * 512 + tap * 256 + d]; }
    else                { int c = col - 384; int f = c & 127; int tap = c >> 7;  v = w3[f * 768 + tap * 256 + d]; }
    Wf[i] = f2b(v);
}

// W_fc [64][512] -> W_fc_t [512][64] fp32
__global__ void k_tr_wfc(const float* __restrict__ src, float* __restrict__ dst){
    int i = blockIdx.x * 256 + threadIdx.x;       // 32768
    int v = i >> 9, k = i & 511;
    dst[k * 64 + v] = src[i];
}

// X[row][d] = bf16(embed[word_ids[row]][d]), row in [0, MX)
__global__ void k_gather(const int* __restrict__ wid, const float* __restrict__ embed,
                         unsigned short* __restrict__ X){
    int i = blockIdx.x * 256 + threadIdx.x;       // MX*64
    int row = i >> 6, d4 = i & 63;
    int w = wid[row];
    float4 v = *(const float4*)(embed + (size_t)w * DD + d4 * 4);
    ushort4 o; o.x = f2b(v.x); o.y = f2b(v.y); o.z = f2b(v.z); o.w = f2b(v.w);
    *(ushort4*)(X + (size_t)row * DD + d4 * 4) = o;
}

// c_w: dec[row][0..256) = mean of 8 X rows
__global__ void k_cw(const unsigned short* __restrict__ X, unsigned short* __restrict__ dec){
    int i = blockIdx.x * 256 + threadIdx.x;       // MROWS*256
    int row = i >> 8, d = i & 255;
    const unsigned short* p = X + (size_t)row * 8 * DD + d;
    float s = 0.f;
#pragma unroll
    for (int t = 0; t < 8; t++) s += b2f(p[t * DD]);
    dec[(size_t)row * DIN + d] = f2b(s * 0.125f);
}

// c_h: dec[row][256..768) = mean of 8 encoder rows
__global__ void k_ch(const float* __restrict__ enc, unsigned short* __restrict__ dec){
    int i = blockIdx.x * 256 + threadIdx.x;       // MROWS*512
    int row = i >> 9, c = i & 511;
    const float* p = enc + (size_t)row * 8 * H2 + c;
    float s = 0.f;
#pragma unroll
    for (int t = 0; t < 8; t++) s += p[t * H2];
    dec[(size_t)row * DIN + 256 + c] = f2b(s * 0.125f);
}

// h0 into Hbuf[0], column-blocked layout: elem (b,c) at (c>>3)*512 + b*8 + (c&7)
__global__ void k_h0(const float* __restrict__ enc, unsigned short* __restrict__ Hbuf){
    int i = blockIdx.x * 256 + threadIdx.x;       // 64*512
    int b = i >> 9, c = i & 511;
    float v = (c < 256) ? enc[(size_t)b * SS * H2 + (size_t)(SS - 1) * H2 + c]
                        : enc[(size_t)b * SS * H2 + c];
    Hbuf[(size_t)(c >> 3) * 512 + b * 8 + (c & 7)] = f2b(v);
}

// ---------------- generic BT GEMM: C[M][N] = A[M][K] * Bm[N][K]^T, bf16 in/out ----------------
__global__ __launch_bounds__(256) void gemm_bt(
    const unsigned short* __restrict__ A, const unsigned short* __restrict__ Bm,
    unsigned short* __restrict__ C, int M, int N, int K)
{
    __shared__ unsigned short As[128][40];
    __shared__ unsigned short Bs[128][40];
    const int tid = threadIdx.x;
    const int m0 = blockIdx.y * 128, n0 = blockIdx.x * 128;
    const int w = tid >> 6, lane = tid & 63;
    const int lm = lane & 15, quad = lane >> 4;
    const int wm = (w >> 1) * 64, wn = (w & 1) * 64;

    const f32x4 z = {0.f, 0.f, 0.f, 0.f};
    f32x4 acc[4][4];
#pragma unroll
    for (int i = 0; i < 4; i++)
#pragma unroll
        for (int j = 0; j < 4; j++) acc[i][j] = z;

    const int r0 = tid >> 2;            // 0..63
    const int kp = (tid & 3) * 8;       // 0,8,16,24 (bf16 units)

    for (int kc = 0; kc < K; kc += 32){
        uint4 a0 = *(const uint4*)(A + (size_t)(m0 + r0) * K + kc + kp);
        uint4 a1 = *(const uint4*)(A + (size_t)(m0 + 64 + r0) * K + kc + kp);
        uint4 b0 = *(const uint4*)(Bm + (size_t)(n0 + r0) * K + kc + kp);
        uint4 b1 = *(const uint4*)(Bm + (size_t)(n0 + 64 + r0) * K + kc + kp);
        __syncthreads();
        *(uint4*)&As[r0][kp] = a0;
        *(uint4*)&As[64 + r0][kp] = a1;
        *(uint4*)&Bs[r0][kp] = b0;
        *(uint4*)&Bs[64 + r0][kp] = b1;
        __syncthreads();
        bf16x8 af[4], bf[4];
#pragma unroll
        for (int mt = 0; mt < 4; mt++) af[mt] = *(const bf16x8*)&As[wm + mt * 16 + lm][quad * 8];
#pragma unroll
        for (int nt = 0; nt < 4; nt++) bf[nt] = *(const bf16x8*)&Bs[wn + nt * 16 + lm][quad * 8];
#pragma unroll
        for (int mt = 0; mt < 4; mt++)
#pragma unroll
            for (int nt = 0; nt < 4; nt++)
                acc[mt][nt] = __builtin_amdgcn_mfma_f32_16x16x32_bf16(af[mt], bf[nt], acc[mt][nt], 0, 0, 0);
    }
#pragma unroll
    for (int mt = 0; mt < 4; mt++){
        int mrow = m0 + wm + mt * 16 + quad * 4;
#pragma unroll
        for (int nt = 0; nt < 4; nt++){
            int ncol = n0 + wn + nt * 16 + lm;
#pragma unroll
            for (int r = 0; r < 4; r++)
                C[(size_t)(mrow + r) * N + ncol] = f2b(acc[mt][nt][r]);
        }
    }
}

// ---- gates GEMM: same compute, epilogue writes blocked layout ----
// dest element (b,t,cb,g,j): offset = (((cb*128 + t)*64 + b)*4 + g)*8 + j
__global__ __launch_bounds__(256) void gemm_bt_gates(
    const unsigned short* __restrict__ A, const unsigned short* __restrict__ Bm,
    unsigned short* __restrict__ C, int M, int N, int K)
{
    __shared__ unsigned short As[128][40];
    __shared__ unsigned short Bs[128][40];
    const int tid = threadIdx.x;
    const int m0 = blockIdx.y * 128, n0 = blockIdx.x * 128;
    const int w = tid >> 6, lane = tid & 63;
    const int lm = lane & 15, quad = lane >> 4;
    const int wm = (w >> 1) * 64, wn = (w & 1) * 64;

    const f32x4 z = {0.f, 0.f, 0.f, 0.f};
    f32x4 acc[4][4];
#pragma unroll
    for (int i = 0; i < 4; i++)
#pragma unroll
        for (int j = 0; j < 4; j++) acc[i][j] = z;

    const int r0 = tid >> 2;
    const int kp = (tid & 3) * 8;

    for (int kc = 0; kc < K; kc += 32){
        uint4 a0 = *(const uint4*)(A + (size_t)(m0 + r0) * K + kc + kp);
        uint4 a1 = *(const uint4*)(A + (size_t)(m0 + 64 + r0) * K + kc + kp);
        uint4 b0 = *(const uint4*)(Bm + (size_t)(n0 + r0) * K + kc + kp);
        uint4 b1 = *(const uint4*)(Bm + (size_t)(n0 + 64 + r0) * K + kc + kp);
        __syncthreads();
        *(uint4*)&As[r0][kp] = a0;
        *(uint4*)&As[64 + r0][kp] = a1;
        *(uint4*)&Bs[r0][kp] = b0;
        *(uint4*)&Bs[64 + r0][kp] = b1;
        __syncthreads();
        bf16x8 af[4], bf[4];
#pragma unroll
        for (int mt = 0; mt < 4; mt++) af[mt] = *(const bf16x8*)&As[wm + mt * 16 + lm][quad * 8];
#pragma unroll
        for (int nt = 0; nt < 4; nt++) bf[nt] = *(const bf16x8*)&Bs[wn + nt * 16 + lm][quad * 8];
#pragma unroll
        for (int mt = 0; mt < 4; mt++)
#pragma unroll
            for (int nt = 0; nt < 4; nt++)
                acc[mt][nt] = __builtin_amdgcn_mfma_f32_16x16x32_bf16(af[mt], bf[nt], acc[mt][nt], 0, 0, 0);
    }
#pragma unroll
    for (int mt = 0; mt < 4; mt++){
        int mrow = m0 + wm + mt * 16 + quad * 4;
#pragma unroll
        for (int nt = 0; nt < 4; nt++){
            int ncol = n0 + wn + nt * 16 + lm;
            int cb = (ncol >> 3) & 63, g = ncol >> 9, j = ncol & 7;
#pragma unroll
            for (int r = 0; r < 4; r++){
                int m = mrow + r;                   // = b*128 + t
                int b = m >> 7, t = m & 127;
                size_t dst = ((((size_t)cb * NSEG + t) * 64 + b) * 4 + g) * 8 + j;
                C[dst] = f2b(acc[mt][nt][r]);
            }
        }
    }
}

// ---------------- conv max-pool: G[MX rows][N] -> dec[:,768+colofs..] ----------------
__global__ void k_pool(const unsigned short* __restrict__ G, const float* __restrict__ bias,
                       unsigned short* __restrict__ dec, int taps, int colofs){
    int i = blockIdx.x * 256 + threadIdx.x;       // MROWS*128
    int row = i >> 7, f = i & 127;
    int N = taps * 128;
    float mx = -1e30f;
    for (int t = 0; t <= 8 - taps; t++){
        float a = 0.f;
        for (int tap = 0; tap < taps; tap++)
            a += b2f(G[(size_t)(row * 8 + t + tap) * N + tap * 128 + f]);
        mx = fmaxf(mx, a);
    }
    mx = fmaxf(mx + bias[f], 0.f);
    dec[(size_t)row * DIN + 768 + colofs + f] = f2b(mx);
}

// ---------------- persistent LSTM recurrence: 64 blocks, per-block flags ----------------
// Hbuf layout per step: [kb:64][b:64][c':8] bf16 (column-blocked; block cb owns kb==cb)
// gxt layout: [cb][t][b][g][j], contiguous 4KB chunk per (cb,t)
__global__ __launch_bounds__(256, 1) void k_lstm(
    const unsigned short* __restrict__ gxt,  // blocked gates, bf16
    const unsigned short* __restrict__ Whh,  // [2048][512] bf16
    unsigned short* __restrict__ Hbuf,       // [129][64*512]
    int* flags)                              // [128][64]
{
    __shared__ unsigned short Wl[32][520];   // rows: 8 i | 8 f | 8 g | 8 o for cols c0..c0+7
    const int tid = threadIdx.x;
    const int cb = blockIdx.x;
    const int c0 = cb * 8;
    const int w = tid >> 6, lane = tid & 63, lm = lane & 15, quad = lane >> 4;

#pragma unroll
    for (int i = 0; i < 8; i++){
        int u = tid + i * 256;                    // 0..2047
        int r = u >> 6, k8 = (u & 63) * 8;
        int g = r >> 3, c = r & 7;
        *(uint4*)&Wl[r][k8] = *(const uint4*)(Whh + (size_t)(g * H2 + c0 + c) * H2 + k8);
    }
    __syncthreads();

    float cst[4] = {0.f, 0.f, 0.f, 0.f};

    for (int t = 0; t < NSEG; t++){
        // --- prefetch this step's gate pre-activations (independent of h) ---
        float pre[4][4];                          // [r][g]
        if (lm < 8){
            const unsigned short* gp = gxt + ((size_t)cb * NSEG + t) * 2048
                                           + (w * 16 + quad * 4) * 32 + lm;
#pragma unroll
            for (int r = 0; r < 4; r++)
#pragma unroll
                for (int g = 0; g < 4; g++)
                    pre[r][g] = b2f(gp[r * 32 + g * 8]);
        }

        // --- wait for all peers' h(t) ---
        if (t > 0){
            if (w == 0){
                int* fp = flags + (t - 1) * 64 + lane;
                int it = 0;
                while (true){
                    if (__hip_atomic_load(fp, __ATOMIC_RELAXED, __HIP_MEMORY_SCOPE_AGENT)) break;
                    __builtin_amdgcn_s_sleep(2);
                    if ((++it & 63) == 0){
                        if (__hip_atomic_fetch_add(fp, 0, __ATOMIC_RELAXED, __HIP_MEMORY_SCOPE_AGENT)) break;
                    }
                }
            }
            __syncthreads();
            __builtin_amdgcn_fence(__ATOMIC_ACQUIRE, "agent");
        }

        const unsigned short* hp = Hbuf + (size_t)t * (BB * H2);
        f32x4 acc0 = {0.f,0.f,0.f,0.f}, acc1 = {0.f,0.f,0.f,0.f};
#pragma unroll
        for (int ks = 0; ks < 16; ks++){
            bf16x8 av = *(const bf16x8*)(hp + (size_t)(ks * 4 + quad) * 512 + (w * 16 + lm) * 8);
            bf16x8 b0 = *(const bf16x8*)&Wl[lm][ks * 32 + quad * 8];
            bf16x8 b1 = *(const bf16x8*)&Wl[16 + lm][ks * 32 + quad * 8];
            acc0 = __builtin_amdgcn_mfma_f32_16x16x32_bf16(av, b0, acc0, 0, 0, 0);
            acc1 = __builtin_amdgcn_mfma_f32_16x16x32_bf16(av, b1, acc1, 0, 0, 0);
        }
        // cols 0..7=i, 8..15=f (acc0); 16..23=g, 24..31=o (acc1). partner lane lm^8 holds f/o.
        float p0[4], p1[4];
#pragma unroll
        for (int r = 0; r < 4; r++){
            p0[r] = __shfl_xor(acc0[r], 8);
            p1[r] = __shfl_xor(acc1[r], 8);
        }
        if (lm < 8){
            unsigned short* hw = Hbuf + (size_t)(t + 1) * (BB * H2) + (size_t)cb * 512 + lm;
#pragma unroll
            for (int r = 0; r < 4; r++){
                int b = w * 16 + quad * 4 + r;
                float iv = acc0[r] + pre[r][0];
                float fv = p0[r]   + pre[r][1];
                float gv = acc1[r] + pre[r][2];
                float ov = p1[r]   + pre[r][3];
                float si = 1.f / (1.f + expf(-iv));
                float sf = 1.f / (1.f + expf(-fv));
                float so = 1.f / (1.f + expf(-ov));
                cst[r] = sf * cst[r] + si * tanhf(gv);
                hw[b * 8] = f2b(so * tanhf(cst[r]));
            }
        }
        __syncthreads();                          // all h stores drained (vmcnt) before fence
        __builtin_amdgcn_fence(__ATOMIC_RELEASE, "agent");
        if (tid == 0)
            __hip_atomic_store(flags + t * 64 + cb, 1, __ATOMIC_RELAXED, __HIP_MEMORY_SCOPE_AGENT);
    }
}

// ---------------- output projection + log_softmax ----------------
__global__ __launch_bounds__(256) void k_out(
    const unsigned short* __restrict__ Hbuf, const float* __restrict__ Wt, float* __restrict__ out)
{
    __shared__ float hsh[4][H2];
    const int w = threadIdx.x >> 6, lane = threadIdx.x & 63;
    const int row = blockIdx.x * 4 + w;          // 0..8191 = b*128 + t
    const int b = row >> 7, t = row & 127;
    const unsigned short* hp = Hbuf + (size_t)(t + 1) * (BB * H2) + b * 8;
    uint4 hv = *(const uint4*)(hp + (size_t)lane * 512);   // kb = lane
    const unsigned short* hs = (const unsigned short*)&hv;
#pragma unroll
    for (int i = 0; i < 8; i++) hsh[w][lane * 8 + i] = b2f(hs[i]);
    __syncthreads();
    float acc = 0.f;
#pragma unroll 8
    for (int k = 0; k < H2; k++)
        acc = fmaf(hsh[w][k], Wt[k * 64 + lane], acc);
    float m = acc;
#pragma unroll
    for (int off = 32; off; off >>= 1) m = fmaxf(m, __shfl_xor(m, off));
    float e = expf(acc - m), s = e;
#pragma unroll
    for (int off = 32; off; off >>= 1) s += __shfl_xor(s, off);
    out[(size_t)row * TT + lane] = acc - m - logf(s);
}

// ---------------- launcher ----------------
extern "C" void kernel_launch(void* const* d_in, const int* in_sizes, int n_in,
                              void* d_out, int out_size, void* d_ws, size_t ws_size,
                              hipStream_t stream)
{
    const int*   wid = (const int*)d_in[0];
    const float* emb = (const float*)d_in[1];
    const float* enc = (const float*)d_in[2];
    const float* wc1 = (const float*)d_in[3];
    const float* bc1 = (const float*)d_in[4];
    const float* wc2 = (const float*)d_in[5];
    const float* bc2 = (const float*)d_in[6];
    const float* wc3 = (const float*)d_in[7];
    const float* bc3 = (const float*)d_in[8];
    const float* wih = (const float*)d_in[9];
    const float* whh = (const float*)d_in[10];
    const float* wfc = (const float*)d_in[11];

    char* ws = (char*)d_ws;
    size_t off = 0;
    auto alloc = [&](size_t bytes) -> void* {
        void* p = ws + off; off += (bytes + 255) & ~(size_t)255; return p;
    };
    unsigned short* X    = (unsigned short*)alloc((size_t)MX * DD * 2);      // 33.5 MB (reused as Hbuf)
    unsigned short* dec  = (unsigned short*)alloc((size_t)MROWS * DIN * 2);  // 18.9 MB
    unsigned short* Gb   = (unsigned short*)alloc((size_t)MX * 384 * 2);     // 50.3 MB (reused as gates)
    unsigned short* Wfb  = (unsigned short*)alloc((size_t)768 * 256 * 2);
    unsigned short* Wihb = (unsigned short*)alloc((size_t)G4 * DIN * 2);
    unsigned short* Whhb = (unsigned short*)alloc((size_t)G4 * H2 * 2);
    float*          Wfct = (float*)alloc((size_t)H2 * TT * 4);
    int*            flags = (int*)alloc((size_t)NSEG * 64 * 4);
    unsigned short* Hbuf  = X;    // X dead after conv GEMM pass 3
    unsigned short* gates = Gb;   // G dead after pool3

    hipMemsetAsync(flags, 0, (size_t)NSEG * 64 * 4, stream);
    k_cvt<<<(G4 * DIN + 255) / 256, 256, 0, stream>>>(wih, Wihb, G4 * DIN);
    k_cvt<<<(G4 * H2 + 255) / 256, 256, 0, stream>>>(whh, Whhb, G4 * H2);
    k_wf<<<768, 256, 0, stream>>>(wc1, wc2, wc3, Wfb);
    k_tr_wfc<<<128, 256, 0, stream>>>(wfc, Wfct);
    k_gather<<<MX / 4, 256, 0, stream>>>(wid, emb, X);
    k_cw<<<MROWS, 256, 0, stream>>>(X, dec);
    k_ch<<<MROWS * 2, 256, 0, stream>>>(enc, dec);

    gemm_bt<<<dim3(1, 512), 256, 0, stream>>>(X, Wfb,                         Gb, MX, 128, 256);
    k_pool<<<4096, 256, 0, stream>>>(Gb, bc1, dec, 1, 0);
    gemm_bt<<<dim3(2, 512), 256, 0, stream>>>(X, Wfb + (size_t)128 * 256,     Gb, MX, 256, 256);
    k_pool<<<4096, 256, 0, stream>>>(Gb, bc2, dec, 2, 128);
    gemm_bt<<<dim3(3, 512), 256, 0, stream>>>(X, Wfb + (size_t)384 * 256,     Gb, MX, 384, 256);
    k_pool<<<4096, 256, 0, stream>>>(Gb, bc3, dec, 3, 256);

    k_h0<<<BB * H2 / 256, 256, 0, stream>>>(enc, Hbuf);   // after last X reader
    gemm_bt_gates<<<dim3(16, 64), 256, 0, stream>>>(dec, Wihb, gates, MROWS, G4, DIN);
    k_lstm<<<64, 256, 0, stream>>>(gates, Whhb, Hbuf, flags);
    k_out<<<2048, 256, 0, stream>>>(Hbuf, Wfct, (float*)d_out);
}

// Round 3
// 1035.981 us; speedup vs baseline: 1.7922x; 1.5730x over previous
//
#include <hip/hip_runtime.h>
#include <math.h>

#define BB   64
#define SS   1024
#define DD   256
#define H2   512
#define FF   128
#define TT   64
#define NSEG 128
#define DIN  1152
#define G4   2048
#define MROWS 8192   /* B*NSEG */
#define MX   65536   /* B*S   */

typedef __attribute__((ext_vector_type(8))) short bf16x8;
typedef __attribute__((ext_vector_type(4))) float f32x4;

__device__ __forceinline__ unsigned short f2b(float f){
    union { float f; unsigned u; } v; v.f = f;
    unsigned r = v.u + 0x7fffu + ((v.u >> 16) & 1u);
    return (unsigned short)(r >> 16);
}
__device__ __forceinline__ float b2f(unsigned short h){
    union { unsigned u; float f; } v; v.u = ((unsigned)h) << 16;
    return v.f;
}

// ---------------- prep kernels ----------------

__global__ void k_cvt(const float* __restrict__ src, unsigned short* __restrict__ dst, int n){
    int i = blockIdx.x * 256 + threadIdx.x;
    if (i < n) dst[i] = f2b(src[i]);
}

// Wf [768][256] rows: 0..127 c1t0 | 128..255 c2t0 | 256..383 c2t1 | 384..511 c3t0 | 512..639 c3t1 | 640..767 c3t2
__global__ void k_wf(const float* __restrict__ w1, const float* __restrict__ w2,
                     const float* __restrict__ w3, unsigned short* __restrict__ Wf){
    int i = blockIdx.x * 256 + threadIdx.x;       // 768*256
    int col = i >> 8, d = i & 255;
    float v;
    if (col < 128)      v = w1[col * 256 + d];
    else if (col < 384) { int f = (col - 128) & 127; int tap = (col - 128) >> 7; v = w2[f * 512 + tap * 256 + d]; }
    else                { int c = col - 384; int f = c & 127; int tap = c >> 7;  v = w3[f * 768 + tap * 256 + d]; }
    Wf[i] = f2b(v);
}

// W_fc [64][512] -> W_fc_t [512][64] fp32
__global__ void k_tr_wfc(const float* __restrict__ src, float* __restrict__ dst){
    int i = blockIdx.x * 256 + threadIdx.x;       // 32768
    int v = i >> 9, k = i & 511;
    dst[k * 64 + v] = src[i];
}

// X[row][d] = bf16(embed[word_ids[row]][d]), row in [0, MX)
__global__ void k_gather(const int* __restrict__ wid, const float* __restrict__ embed,
                         unsigned short* __restrict__ X){
    int i = blockIdx.x * 256 + threadIdx.x;       // MX*64
    int row = i >> 6, d4 = i & 63;
    int w = wid[row];
    float4 v = *(const float4*)(embed + (size_t)w * DD + d4 * 4);
    ushort4 o; o.x = f2b(v.x); o.y = f2b(v.y); o.z = f2b(v.z); o.w = f2b(v.w);
    *(ushort4*)(X + (size_t)row * DD + d4 * 4) = o;
}

// c_w: dec[row][0..256) = mean of 8 X rows
__global__ void k_cw(const unsigned short* __restrict__ X, unsigned short* __restrict__ dec){
    int i = blockIdx.x * 256 + threadIdx.x;       // MROWS*256
    int row = i >> 8, d = i & 255;
    const unsigned short* p = X + (size_t)row * 8 * DD + d;
    float s = 0.f;
#pragma unroll
    for (int t = 0; t < 8; t++) s += b2f(p[t * DD]);
    dec[(size_t)row * DIN + d] = f2b(s * 0.125f);
}

// c_h: dec[row][256..768) = mean of 8 encoder rows
__global__ void k_ch(const float* __restrict__ enc, unsigned short* __restrict__ dec){
    int i = blockIdx.x * 256 + threadIdx.x;       // MROWS*512
    int row = i >> 9, c = i & 511;
    const float* p = enc + (size_t)row * 8 * H2 + c;
    float s = 0.f;
#pragma unroll
    for (int t = 0; t < 8; t++) s += p[t * H2];
    dec[(size_t)row * DIN + 256 + c] = f2b(s * 0.125f);
}

// h0 into Hbuf[0], column-blocked layout: elem (b,c) at (c>>3)*512 + b*8 + (c&7)
__global__ void k_h0(const float* __restrict__ enc, unsigned short* __restrict__ Hbuf){
    int i = blockIdx.x * 256 + threadIdx.x;       // 64*512
    int b = i >> 9, c = i & 511;
    float v = (c < 256) ? enc[(size_t)b * SS * H2 + (size_t)(SS - 1) * H2 + c]
                        : enc[(size_t)b * SS * H2 + c];
    Hbuf[(size_t)(c >> 3) * 512 + b * 8 + (c & 7)] = f2b(v);
}

// ---------------- generic BT GEMM: C[M][N] = A[M][K] * Bm[N][K]^T, bf16 in/out ----------------
__global__ __launch_bounds__(256) void gemm_bt(
    const unsigned short* __restrict__ A, const unsigned short* __restrict__ Bm,
    unsigned short* __restrict__ C, int M, int N, int K)
{
    __shared__ unsigned short As[128][40];
    __shared__ unsigned short Bs[128][40];
    const int tid = threadIdx.x;
    const int m0 = blockIdx.y * 128, n0 = blockIdx.x * 128;
    const int w = tid >> 6, lane = tid & 63;
    const int lm = lane & 15, quad = lane >> 4;
    const int wm = (w >> 1) * 64, wn = (w & 1) * 64;

    const f32x4 z = {0.f, 0.f, 0.f, 0.f};
    f32x4 acc[4][4];
#pragma unroll
    for (int i = 0; i < 4; i++)
#pragma unroll
        for (int j = 0; j < 4; j++) acc[i][j] = z;

    const int r0 = tid >> 2;            // 0..63
    const int kp = (tid & 3) * 8;       // 0,8,16,24 (bf16 units)

    for (int kc = 0; kc < K; kc += 32){
        uint4 a0 = *(const uint4*)(A + (size_t)(m0 + r0) * K + kc + kp);
        uint4 a1 = *(const uint4*)(A + (size_t)(m0 + 64 + r0) * K + kc + kp);
        uint4 b0 = *(const uint4*)(Bm + (size_t)(n0 + r0) * K + kc + kp);
        uint4 b1 = *(const uint4*)(Bm + (size_t)(n0 + 64 + r0) * K + kc + kp);
        __syncthreads();
        *(uint4*)&As[r0][kp] = a0;
        *(uint4*)&As[64 + r0][kp] = a1;
        *(uint4*)&Bs[r0][kp] = b0;
        *(uint4*)&Bs[64 + r0][kp] = b1;
        __syncthreads();
        bf16x8 af[4], bf[4];
#pragma unroll
        for (int mt = 0; mt < 4; mt++) af[mt] = *(const bf16x8*)&As[wm + mt * 16 + lm][quad * 8];
#pragma unroll
        for (int nt = 0; nt < 4; nt++) bf[nt] = *(const bf16x8*)&Bs[wn + nt * 16 + lm][quad * 8];
#pragma unroll
        for (int mt = 0; mt < 4; mt++)
#pragma unroll
            for (int nt = 0; nt < 4; nt++)
                acc[mt][nt] = __builtin_amdgcn_mfma_f32_16x16x32_bf16(af[mt], bf[nt], acc[mt][nt], 0, 0, 0);
    }
#pragma unroll
    for (int mt = 0; mt < 4; mt++){
        int mrow = m0 + wm + mt * 16 + quad * 4;
#pragma unroll
        for (int nt = 0; nt < 4; nt++){
            int ncol = n0 + wn + nt * 16 + lm;
#pragma unroll
            for (int r = 0; r < 4; r++)
                C[(size_t)(mrow + r) * N + ncol] = f2b(acc[mt][nt][r]);
        }
    }
}

// ---- gates GEMM: same compute, epilogue writes blocked layout ----
// dest element (b,t,cb,g,j): offset = (((cb*128 + t)*64 + b)*4 + g)*8 + j
__global__ __launch_bounds__(256) void gemm_bt_gates(
    const unsigned short* __restrict__ A, const unsigned short* __restrict__ Bm,
    unsigned short* __restrict__ C, int M, int N, int K)
{
    __shared__ unsigned short As[128][40];
    __shared__ unsigned short Bs[128][40];
    const int tid = threadIdx.x;
    const int m0 = blockIdx.y * 128, n0 = blockIdx.x * 128;
    const int w = tid >> 6, lane = tid & 63;
    const int lm = lane & 15, quad = lane >> 4;
    const int wm = (w >> 1) * 64, wn = (w & 1) * 64;

    const f32x4 z = {0.f, 0.f, 0.f, 0.f};
    f32x4 acc[4][4];
#pragma unroll
    for (int i = 0; i < 4; i++)
#pragma unroll
        for (int j = 0; j < 4; j++) acc[i][j] = z;

    const int r0 = tid >> 2;
    const int kp = (tid & 3) * 8;

    for (int kc = 0; kc < K; kc += 32){
        uint4 a0 = *(const uint4*)(A + (size_t)(m0 + r0) * K + kc + kp);
        uint4 a1 = *(const uint4*)(A + (size_t)(m0 + 64 + r0) * K + kc + kp);
        uint4 b0 = *(const uint4*)(Bm + (size_t)(n0 + r0) * K + kc + kp);
        uint4 b1 = *(const uint4*)(Bm + (size_t)(n0 + 64 + r0) * K + kc + kp);
        __syncthreads();
        *(uint4*)&As[r0][kp] = a0;
        *(uint4*)&As[64 + r0][kp] = a1;
        *(uint4*)&Bs[r0][kp] = b0;
        *(uint4*)&Bs[64 + r0][kp] = b1;
        __syncthreads();
        bf16x8 af[4], bf[4];
#pragma unroll
        for (int mt = 0; mt < 4; mt++) af[mt] = *(const bf16x8*)&As[wm + mt * 16 + lm][quad * 8];
#pragma unroll
        for (int nt = 0; nt < 4; nt++) bf[nt] = *(const bf16x8*)&Bs[wn + nt * 16 + lm][quad * 8];
#pragma unroll
        for (int mt = 0; mt < 4; mt++)
#pragma unroll
            for (int nt = 0; nt < 4; nt++)
                acc[mt][nt] = __builtin_amdgcn_mfma_f32_16x16x32_bf16(af[mt], bf[nt], acc[mt][nt], 0, 0, 0);
    }
#pragma unroll
    for (int mt = 0; mt < 4; mt++){
        int mrow = m0 + wm + mt * 16 + quad * 4;
#pragma unroll
        for (int nt = 0; nt < 4; nt++){
            int ncol = n0 + wn + nt * 16 + lm;
            int cb = (ncol >> 3) & 63, g = ncol >> 9, j = ncol & 7;
#pragma unroll
            for (int r = 0; r < 4; r++){
                int m = mrow + r;                   // = b*128 + t
                int b = m >> 7, t = m & 127;
                size_t dst = ((((size_t)cb * NSEG + t) * 64 + b) * 4 + g) * 8 + j;
                C[dst] = f2b(acc[mt][nt][r]);
            }
        }
    }
}

// ---------------- conv max-pool: G[MX rows][N] -> dec[:,768+colofs..] ----------------
__global__ void k_pool(const unsigned short* __restrict__ G, const float* __restrict__ bias,
                       unsigned short* __restrict__ dec, int taps, int colofs){
    int i = blockIdx.x * 256 + threadIdx.x;       // MROWS*128
    int row = i >> 7, f = i & 127;
    int N = taps * 128;
    float mx = -1e30f;
    for (int t = 0; t <= 8 - taps; t++){
        float a = 0.f;
        for (int tap = 0; tap < taps; tap++)
            a += b2f(G[(size_t)(row * 8 + t + tap) * N + tap * 128 + f]);
        mx = fmaxf(mx, a);
    }
    mx = fmaxf(mx + bias[f], 0.f);
    dec[(size_t)row * DIN + 768 + colofs + f] = f2b(mx);
}

// ---------------- persistent LSTM recurrence: 64 blocks, fence-free coherent flags ----------------
// All cross-block traffic (h, flags) uses relaxed AGENT-scope atomics: per-access
// coherent (bypasses L1/per-XCD L2), so NO agent fences (wbl2/inv) are needed.
// Ordering: compiler emits s_waitcnt vmcnt(0) before s_barrier, so every wave's h
// stores reach the coherence point before tid0 publishes the flag.
// Hbuf layout per step: [kb:64][b:64][c':8] bf16 (column-blocked; block cb owns kb==cb)
// gxt layout: [cb][t][b][g][j], contiguous 4KB chunk per (cb,t)
__global__ __launch_bounds__(256, 1) void k_lstm(
    const unsigned short* __restrict__ gxt,  // blocked gates, bf16
    const unsigned short* __restrict__ Whh,  // [2048][512] bf16
    unsigned short* __restrict__ Hbuf,       // [129][64*512]
    int* flags)                              // [128][64]
{
    __shared__ unsigned short Wl[32][520];   // rows: 8 i | 8 f | 8 g | 8 o for cols c0..c0+7
    const int tid = threadIdx.x;
    const int cb = blockIdx.x;
    const int c0 = cb * 8;
    const int w = tid >> 6, lane = tid & 63, lm = lane & 15, quad = lane >> 4;

#pragma unroll
    for (int i = 0; i < 8; i++){
        int u = tid + i * 256;                    // 0..2047
        int r = u >> 6, k8 = (u & 63) * 8;
        int g = r >> 3, c = r & 7;
        *(uint4*)&Wl[r][k8] = *(const uint4*)(Whh + (size_t)(g * H2 + c0 + c) * H2 + k8);
    }
    __syncthreads();

    float cst[4] = {0.f, 0.f, 0.f, 0.f};

    for (int t = 0; t < NSEG; t++){
        // --- prefetch this step's gate pre-activations (independent of h) ---
        float pre[4][4];                          // [r][g]
        if (lm < 8){
            const unsigned short* gp = gxt + ((size_t)cb * NSEG + t) * 2048
                                           + (w * 16 + quad * 4) * 32 + lm;
#pragma unroll
            for (int r = 0; r < 4; r++)
#pragma unroll
                for (int g = 0; g < 4; g++)
                    pre[r][g] = b2f(gp[r * 32 + g * 8]);
        }

        // --- wait for all peers' h(t) flags (relaxed coherent loads, no fence) ---
        if (t > 0){
            if (w == 0){
                int* fp = flags + (t - 1) * 64 + lane;
                while (!__hip_atomic_load(fp, __ATOMIC_RELAXED, __HIP_MEMORY_SCOPE_AGENT))
                    __builtin_amdgcn_s_sleep(1);
            }
            __syncthreads();
        }

        // --- coherent h(t) reads: relaxed agent atomics (pipelined, independent) ---
        const unsigned short* hp = Hbuf + (size_t)t * (BB * H2);
        f32x4 acc0 = {0.f,0.f,0.f,0.f}, acc1 = {0.f,0.f,0.f,0.f};
#pragma unroll
        for (int ks = 0; ks < 16; ks++){
            const unsigned long long* ap =
                (const unsigned long long*)(hp + (size_t)(ks * 4 + quad) * 512 + (w * 16 + lm) * 8);
            union { unsigned long long q[2]; bf16x8 v; } u;
            u.q[0] = __hip_atomic_load(ap,     __ATOMIC_RELAXED, __HIP_MEMORY_SCOPE_AGENT);
            u.q[1] = __hip_atomic_load(ap + 1, __ATOMIC_RELAXED, __HIP_MEMORY_SCOPE_AGENT);
            bf16x8 av = u.v;
            bf16x8 b0 = *(const bf16x8*)&Wl[lm][ks * 32 + quad * 8];
            bf16x8 b1 = *(const bf16x8*)&Wl[16 + lm][ks * 32 + quad * 8];
            acc0 = __builtin_amdgcn_mfma_f32_16x16x32_bf16(av, b0, acc0, 0, 0, 0);
            acc1 = __builtin_amdgcn_mfma_f32_16x16x32_bf16(av, b1, acc1, 0, 0, 0);
        }
        // cols 0..7=i, 8..15=f (acc0); 16..23=g, 24..31=o (acc1). partner lane lm^8 holds f/o.
        float p0[4], p1[4];
#pragma unroll
        for (int r = 0; r < 4; r++){
            p0[r] = __shfl_xor(acc0[r], 8);
            p1[r] = __shfl_xor(acc1[r], 8);
        }
        if (lm < 8){
            unsigned short* hwbase = Hbuf + (size_t)(t + 1) * (BB * H2) + (size_t)cb * 512;
#pragma unroll
            for (int r = 0; r < 4; r++){
                int b = w * 16 + quad * 4 + r;
                float iv = acc0[r] + pre[r][0];
                float fv = p0[r]   + pre[r][1];
                float gv = acc1[r] + pre[r][2];
                float ov = p1[r]   + pre[r][3];
                float si = 1.f / (1.f + expf(-iv));
                float sf = 1.f / (1.f + expf(-fv));
                float so = 1.f / (1.f + expf(-ov));
                cst[r] = sf * cst[r] + si * tanhf(gv);
                unsigned short hv16 = f2b(so * tanhf(cst[r]));
                unsigned short prt = (unsigned short)__shfl_xor((int)hv16, 1);
                if (!(lm & 1)){
                    unsigned int packed = (unsigned)hv16 | ((unsigned)prt << 16);
                    __hip_atomic_store((unsigned int*)(hwbase + b * 8 + lm), packed,
                                       __ATOMIC_RELAXED, __HIP_MEMORY_SCOPE_AGENT);
                }
            }
        }
        __syncthreads();   // compiler drains vmcnt(0) before s_barrier -> h at coherence point
        if (tid == 0)
            __hip_atomic_store(flags + t * 64 + cb, 1, __ATOMIC_RELAXED, __HIP_MEMORY_SCOPE_AGENT);
    }
}

// ---------------- output projection + log_softmax ----------------
__global__ __launch_bounds__(256) void k_out(
    const unsigned short* __restrict__ Hbuf, const float* __restrict__ Wt, float* __restrict__ out)
{
    __shared__ float hsh[4][H2];
    const int w = threadIdx.x >> 6, lane = threadIdx.x & 63;
    const int row = blockIdx.x * 4 + w;          // 0..8191 = b*128 + t
    const int b = row >> 7, t = row & 127;
    const unsigned short* hp = Hbuf + (size_t)(t + 1) * (BB * H2) + b * 8;
    uint4 hv = *(const uint4*)(hp + (size_t)lane * 512);   // kb = lane
    const unsigned short* hs = (const unsigned short*)&hv;
#pragma unroll
    for (int i = 0; i < 8; i++) hsh[w][lane * 8 + i] = b2f(hs[i]);
    __syncthreads();
    float acc = 0.f;
#pragma unroll 8
    for (int k = 0; k < H2; k++)
        acc = fmaf(hsh[w][k], Wt[k * 64 + lane], acc);
    float m = acc;
#pragma unroll
    for (int off = 32; off; off >>= 1) m = fmaxf(m, __shfl_xor(m, off));
    float e = expf(acc - m), s = e;
#pragma unroll
    for (int off = 32; off; off >>= 1) s += __shfl_xor(s, off);
    out[(size_t)row * TT + lane] = acc - m - logf(s);
}

// ---------------- launcher ----------------
extern "C" void kernel_launch(void* const* d_in, const int* in_sizes, int n_in,
                              void* d_out, int out_size, void* d_ws, size_t ws_size,
                              hipStream_t stream)
{
    const int*   wid = (const int*)d_in[0];
    const float* emb = (const float*)d_in[1];
    const float* enc = (const float*)d_in[2];
    const float* wc1 = (const float*)d_in[3];
    const float* bc1 = (const float*)d_in[4];
    const float* wc2 = (const float*)d_in[5];
    const float* bc2 = (const float*)d_in[6];
    const float* wc3 = (const float*)d_in[7];
    const float* bc3 = (const float*)d_in[8];
    const float* wih = (const float*)d_in[9];
    const float* whh = (const float*)d_in[10];
    const float* wfc = (const float*)d_in[11];

    char* ws = (char*)d_ws;
    size_t off = 0;
    auto alloc = [&](size_t bytes) -> void* {
        void* p = ws + off; off += (bytes + 255) & ~(size_t)255; return p;
    };
    unsigned short* X    = (unsigned short*)alloc((size_t)MX * DD * 2);      // 33.5 MB (reused as Hbuf)
    unsigned short* dec  = (unsigned short*)alloc((size_t)MROWS * DIN * 2);  // 18.9 MB
    unsigned short* Gb   = (unsigned short*)alloc((size_t)MX * 384 * 2);     // 50.3 MB (reused as gates)
    unsigned short* Wfb  = (unsigned short*)alloc((size_t)768 * 256 * 2);
    unsigned short* Wihb = (unsigned short*)alloc((size_t)G4 * DIN * 2);
    unsigned short* Whhb = (unsigned short*)alloc((size_t)G4 * H2 * 2);
    float*          Wfct = (float*)alloc((size_t)H2 * TT * 4);
    int*            flags = (int*)alloc((size_t)NSEG * 64 * 4);
    unsigned short* Hbuf  = X;    // X dead after conv GEMM pass 3
    unsigned short* gates = Gb;   // G dead after pool3

    hipMemsetAsync(flags, 0, (size_t)NSEG * 64 * 4, stream);
    k_cvt<<<(G4 * DIN + 255) / 256, 256, 0, stream>>>(wih, Wihb, G4 * DIN);
    k_cvt<<<(G4 * H2 + 255) / 256, 256, 0, stream>>>(whh, Whhb, G4 * H2);
    k_wf<<<768, 256, 0, stream>>>(wc1, wc2, wc3, Wfb);
    k_tr_wfc<<<128, 256, 0, stream>>>(wfc, Wfct);
    k_gather<<<MX / 4, 256, 0, stream>>>(wid, emb, X);
    k_cw<<<MROWS, 256, 0, stream>>>(X, dec);
    k_ch<<<MROWS * 2, 256, 0, stream>>>(enc, dec);

    gemm_bt<<<dim3(1, 512), 256, 0, stream>>>(X, Wfb,                         Gb, MX, 128, 256);
    k_pool<<<4096, 256, 0, stream>>>(Gb, bc1, dec, 1, 0);
    gemm_bt<<<dim3(2, 512), 256, 0, stream>>>(X, Wfb + (size_t)128 * 256,     Gb, MX, 256, 256);
    k_pool<<<4096, 256, 0, stream>>>(Gb, bc2, dec, 2, 128);
    gemm_bt<<<dim3(3, 512), 256, 0, stream>>>(X, Wfb + (size_t)384 * 256,     Gb, MX, 384, 256);
    k_pool<<<4096, 256, 0, stream>>>(Gb, bc3, dec, 3, 256);

    k_h0<<<BB * H2 / 256, 256, 0, stream>>>(enc, Hbuf);   // after last X reader
    gemm_bt_gates<<<dim3(16, 64), 256, 0, stream>>>(dec, Wihb, gates, MROWS, G4, DIN);
    k_lstm<<<64, 256, 0, stream>>>(gates, Whhb, Hbuf, flags);
    k_out<<<2048, 256, 0, stream>>>(Hbuf, Wfct, (float*)d_out);
}